// Round 9
// baseline (333.988 us; speedup 1.0000x reference)
//
#include <hip/hip_runtime.h>
#include <hip/hip_bf16.h>

constexpr int BN = 8, HH = 512, WW = 512;
constexpr int PIX = HH * WW;
constexpr float EPSF = 1e-4f;

__device__ __forceinline__ float b2f(__hip_bfloat16 x) { return __bfloat162float(x); }
__device__ __forceinline__ __hip_bfloat16 f2b(float x) { return __float2bfloat16(x); }
__device__ __forceinline__ unsigned short bfbits(float x) {
    union { __hip_bfloat16 b; unsigned short u; } cv; cv.b = f2b(x); return cv.u;
}

typedef __attribute__((ext_vector_type(8))) short bf16x8;   // MFMA A/B frag
typedef __attribute__((ext_vector_type(4))) float f32x4;    // MFMA C/D frag

// ---- workspace float offsets ----
constexpr int OFF_TOT = 0;       // 8*16 per-image channel totals (atomics)
constexpr int OFF_ROW0 = 128;
constexpr int OFF_ROW1 = 256;
constexpr int OFF_COL0 = 384;
constexpr int OFF_COL1 = 512;
constexpr int OFF_COR = 640;     // corners [b][hi][wi][16] (plain stores)
constexpr int OFF_WR  = 2048;    // A-fragment weights hi(2560 bf16) + lo(2560 bf16)
constexpr size_t WS_NEEDED = 65536;   // small region only — no big buffers anymore

// ---------------- prep: zero atomic slots, swizzle w2 into hi/lo A-fragments ----------------
// hi = rn-bf16(w), lo = rn-bf16(w - hi): split keeps mean(s) at ~fp32 accuracy (round-4 lesson:
// bf16-only w2 flips the discontinuous ceil() in fs -> pi-flips in Hf).
__global__ void prep_kernel(const float* __restrict__ w2, float* __restrict__ wsf) {
    int t = threadIdx.x;
    for (int i = t; i < 640; i += 256) wsf[i] = 0.f;
    unsigned short* ab = (unsigned short*)(wsf + OFF_WR);
    for (int idx = t; idx < 5120; idx += 256) {
        int part = idx / 2560;
        int id = idx - part * 2560;
        int ks = id >> 9, rem = id & 511, lane = rem >> 3, j = id & 7;
        int oc = lane & 15, q = lane >> 4;
        int k = q * 8 + j;
        int tap = 2 * ks + (k >> 4), ic = k & 15;
        float val = (tap <= 8) ? w2[oc * 144 + ic * 9 + tap] : 0.f;
        float hv = b2f(f2b(val));
        ab[idx] = (part == 0) ? bfbits(val) : bfbits(val - hv);
    }
}

__device__ __forceinline__ void conv1_px(const float v[27], const float* __restrict__ w1,
                                         const float* __restrict__ b1, unsigned int u[8]) {
    float o[16];
#pragma unroll
    for (int oc = 0; oc < 16; oc++) {
        float a = b1[oc];
#pragma unroll
        for (int j = 0; j < 27; j++) a += v[j] * w1[oc * 27 + j];
        o[oc] = a / (1.f + __expf(-a));
    }
#pragma unroll
    for (int k = 0; k < 8; k++)
        u[k] = (unsigned int)bfbits(o[2 * k]) | ((unsigned int)bfbits(o[2 * k + 1]) << 16);
}

// ---------------- fused conv1+conv2(+RGB) with conv3-mean reduction ----------------
// NEW: batch tile staged in LDS first — conv1 reads LDS (stride-1), killing ~120
// address-heavy VMEM ops per thread that made VALUBusy 4x the real math.
__global__ __launch_bounds__(256) void conv12_kernel(const float* __restrict__ batch,
                                                     const float* __restrict__ w1,
                                                     const float* __restrict__ b1,
                                                     const unsigned short* __restrict__ abuf,
                                                     const float* __restrict__ b2v,
                                                     float* __restrict__ wsf,
                                                     float* __restrict__ out) {
    __shared__ float sbat[3][20][68];      // 16,320 B  batch tile rows h0-2..h0+17, cols w0-2..w0+65
    __shared__ uint4 h1s[18 * 66 * 2];     // 38,016 B
    __shared__ float part[4][16];

    int tx = threadIdx.x;
    int lane = tx & 63, wave = tx >> 6;
    int n = lane & 15, q = lane >> 4;
    int w0 = blockIdx.x * 64, h0 = blockIdx.y * 16, b = blockIdx.z;
    bool edge = (blockIdx.x == 0) || (blockIdx.x == 7) || (blockIdx.y == 0) || (blockIdx.y == 31);

    union { uint4 u; bf16x8 v; } cv;
    bf16x8 ah[5], al[5];
    const uint4* ab4 = (const uint4*)abuf;
#pragma unroll
    for (int ks = 0; ks < 5; ks++) {
        cv.u = ab4[ks * 64 + lane];       ah[ks] = cv.v;
        cv.u = ab4[320 + ks * 64 + lane]; al[ks] = cv.v;
    }

    const float* pb = batch + (size_t)(b * 3) * PIX;
    // ---- phase 0: stage batch tile (coalesced, ~16 loads/thread) ----
    for (int i = tx; i < 4080; i += 256) {
        int ch = i / 1360, rem = i - ch * 1360, r = rem / 68, c = rem - r * 68;
        int gh = h0 - 2 + r, gw = w0 - 2 + c;
        float x = 0.f;
        if (!edge || (gh >= 0 && gh < HH && gw >= 0 && gw < WW))
            x = pb[(size_t)ch * PIX + (size_t)gh * WW + gw];
        sbat[ch][r][c] = x;
    }
    __syncthreads();

    // ---- phase 1: conv1 from LDS into h1s (66x18 incl. halo) ----
    for (int i = tx; i < 18 * 66; i += 256) {
        int r = i / 66, c = i - r * 66;
        int gh = h0 - 1 + r, gw = w0 - 1 + c;
        unsigned int u[8];
        bool valid = !edge || (gh >= 0 && gh < HH && gw >= 0 && gw < WW);
        if (valid) {
            float v[27];
#pragma unroll
            for (int ic = 0; ic < 3; ic++)
#pragma unroll
                for (int kh = 0; kh < 3; kh++)
#pragma unroll
                    for (int kw = 0; kw < 3; kw++)
                        v[ic * 9 + kh * 3 + kw] = sbat[ic][r + kh][c + kw];
            conv1_px(v, w1, b1, u);
        } else {
#pragma unroll
            for (int k = 0; k < 8; k++) u[k] = 0u;
        }
        int swz = (c >> 2) & 1;
        int base = i * 2;
        h1s[base + swz]       = make_uint4(u[0], u[1], u[2], u[3]);
        h1s[base + (swz ^ 1)] = make_uint4(u[4], u[5], u[6], u[7]);
    }

    // ---- phase 1b: RGB_order from LDS ----
    for (int j = tx; j < 1024; j += 256) {
        int rr = j >> 6, ccx = j & 63;
        float v0 = sbat[0][rr + 2][ccx + 2];
        float v1 = sbat[1][rr + 2][ccx + 2];
        float v2 = sbat[2][rr + 2][ccx + 2];
        size_t p = (size_t)(h0 + rr) * WW + (w0 + ccx);
        int mx  = (v0 >= v1 && v0 >= v2) ? 0 : ((v1 >= v2) ? 1 : 2);
        int mx2 = (v2 >= v1 && v2 >= v0) ? 2 : ((v1 >= v0) ? 1 : 0);
        int mn  = (v0 <= v1 && v0 <= v2) ? 0 : ((v1 <= v2) ? 1 : 2);
        int mn2 = (v2 <= v1 && v2 <= v0) ? 2 : ((v1 <= v0) ? 1 : 0);
#pragma unroll
        for (int c = 0; c < 3; c++) {
            float r = 0.5f * ((float)(c == mx) + (float)(c == mx2))
                    - 0.5f * ((float)(c == mn) + (float)(c == mn2));
            out[(size_t)(b * 6 + 2 + c) * PIX + p] = r;
        }
    }
    __syncthreads();

    // ---- phase 2: conv2 MFMA from LDS (unchanged) ----
    float tt[4] = {0, 0, 0, 0};
    float cs0[4] = {0, 0, 0, 0};
    float cs1[4] = {0, 0, 0, 0};
    for (int rloc = 0; rloc < 4; rloc++) {
        int row = wave * 4 + rloc;
        int grow = h0 + row;
        f32x4 acc[4] = {{0,0,0,0},{0,0,0,0},{0,0,0,0},{0,0,0,0}};
#pragma unroll
        for (int ks = 0; ks < 5; ks++) {
            int tap = 2 * ks + (q >> 1); if (tap > 8) tap = 8;
            int dh = tap / 3 - 1, dw = tap % 3 - 1;
            int half = q & 1;
            int lr = row + 1 + dh;
#pragma unroll
            for (int t = 0; t < 4; t++) {
                int c = 1 + dw + t * 16 + n;
                cv.u = h1s[(lr * 66 + c) * 2 + (half ^ ((c >> 2) & 1))];
                acc[t] = __builtin_amdgcn_mfma_f32_16x16x32_bf16(ah[ks], cv.v, acc[t], 0, 0, 0);
                acc[t] = __builtin_amdgcn_mfma_f32_16x16x32_bf16(al[ks], cv.v, acc[t], 0, 0, 0);
            }
        }
        float sv[4][4];
#pragma unroll
        for (int t = 0; t < 4; t++)
#pragma unroll
            for (int r = 0; r < 4; r++) {
                float a = acc[t][r] + b2v[q * 4 + r];
                sv[t][r] = a / (1.f + __expf(-a));
            }
#pragma unroll
        for (int r = 0; r < 4; r++) tt[r] += sv[0][r] + sv[1][r] + sv[2][r] + sv[3][r];
        if (grow == 0 || grow == HH - 1) {
            int off = (grow == 0) ? OFF_ROW0 : OFF_ROW1;
#pragma unroll
            for (int r = 0; r < 4; r++) {
                float x = sv[0][r] + sv[1][r] + sv[2][r] + sv[3][r];
#pragma unroll
                for (int d = 1; d < 16; d <<= 1) x += __shfl_xor(x, d, 64);
                if (n == 0) atomicAdd(&wsf[off + b * 16 + q * 4 + r], x);
            }
        }
        if (blockIdx.x == 0 && n == 0)
#pragma unroll
            for (int r = 0; r < 4; r++) cs0[r] += sv[0][r];
        if (blockIdx.x == 7 && n == 15)
#pragma unroll
            for (int r = 0; r < 4; r++) cs1[r] += sv[3][r];
        if ((grow == 0 || grow == HH - 1)) {
            int hi = (grow == 0) ? 0 : 1;
            if (blockIdx.x == 0 && n == 0)
#pragma unroll
                for (int r = 0; r < 4; r++)
                    wsf[OFF_COR + ((b * 2 + hi) * 2 + 0) * 16 + q * 4 + r] = sv[0][r];
            if (blockIdx.x == 7 && n == 15)
#pragma unroll
                for (int r = 0; r < 4; r++)
                    wsf[OFF_COR + ((b * 2 + hi) * 2 + 1) * 16 + q * 4 + r] = sv[3][r];
        }
    }
    if (blockIdx.x == 0 && n == 0)
#pragma unroll
        for (int r = 0; r < 4; r++) atomicAdd(&wsf[OFF_COL0 + b * 16 + q * 4 + r], cs0[r]);
    if (blockIdx.x == 7 && n == 15)
#pragma unroll
        for (int r = 0; r < 4; r++) atomicAdd(&wsf[OFF_COL1 + b * 16 + q * 4 + r], cs1[r]);
#pragma unroll
    for (int r = 0; r < 4; r++) {
        float x = tt[r];
#pragma unroll
        for (int d = 1; d < 16; d <<= 1) x += __shfl_xor(x, d, 64);
        tt[r] = x;
    }
    if (n == 0)
#pragma unroll
        for (int r = 0; r < 4; r++) part[wave][q * 4 + r] = tt[r];
    __syncthreads();
    if (tx < 16)
        atomicAdd(&wsf[OFF_TOT + b * 16 + tx],
                  part[0][tx] + part[1][tx] + part[2][tx] + part[3][tx]);
}

// ---------------- strip kernel: taps + horiz + vert fused, tpl lives in an LDS ring ----------------
// Block = 64-col x 128-row strip of one image. tpl never touches HBM.
__global__ __launch_bounds__(256) void strip_kernel(const float* __restrict__ batch,
                                                    const float* __restrict__ gcm,
                                                    const float* __restrict__ w3,
                                                    const float* __restrict__ b3,
                                                    const float* __restrict__ wsf,
                                                    float* __restrict__ out) {
    __shared__ float tplb[68][4][64];      // 69,632 B ring: tpl rows (mod 68)
    __shared__ float xst[16][3][104];      // 19,968 B xg staging (row stride 104 -> 16B-aligned)
    __shared__ float leh[37], lch[37];
    __shared__ float red[160];
    __shared__ float smean, sSe, sSc;

    int tx = threadIdx.x;
    int c0 = blockIdx.x * 64, r0 = blockIdx.y * 128, b = blockIdx.z;
    const float* pb = batch + (size_t)(b * 3) * PIX;

    // ---- phase A: per-block tap computation (bitwise-identical to old filter_kernel) ----
    {
        float val = 0.f;
        if (tx < 144) {
            int ic = tx / 9, tap = tx % 9, kh = tap / 3, kw = tap % 3;
            float T = wsf[OFF_TOT + b * 16 + ic];
            int hi = -1, wi = -1;
            if (kh == 0) { T -= wsf[OFF_ROW1 + b * 16 + ic]; hi = 1; }
            else if (kh == 2) { T -= wsf[OFF_ROW0 + b * 16 + ic]; hi = 0; }
            if (kw == 0) { T -= wsf[OFF_COL1 + b * 16 + ic]; wi = 1; }
            else if (kw == 2) { T -= wsf[OFF_COL0 + b * 16 + ic]; wi = 0; }
            if (hi >= 0 && wi >= 0) T += wsf[OFF_COR + ((b * 2 + hi) * 2 + wi) * 16 + ic];
            val = w3[tx] * T;
        }
        if (tx < 160) red[tx] = val;
        __syncthreads();
        if (tx == 0) {
            float S = 0.f;
            for (int i = 0; i < 144; i++) S += red[i];
            smean = b3[0] + S * (1.f / (float)PIX);
        }
        __syncthreads();
        float scale = fminf(2.5f, fmaxf(-2.5f, smean));
        float sd = exp2f(scale);
        float fs = ceilf(3.f * sd + 0.5f);
        float e = 0.f, c = 0.f;
        if (tx < 37) {
            float x = (float)(tx - 18);
            if (fabsf(x) <= fs) {
                float qq = x / sd;
                e = __expf(-0.5f * qq * qq);
                c = -x / (sd * sd * sd * 6.28318530717958647692f) * e;
            }
            red[tx] = e; red[40 + tx] = fabsf(c);
        }
        __syncthreads();
        if (tx == 0) {
            float a = 0.f, d = 0.f;
            for (int i = 0; i < 37; i++) { a += red[i]; d += red[40 + i]; }
            sSe = a; sSc = d;
        }
        __syncthreads();
        if (tx < 37) { leh[tx] = e / sSe; lch[tx] = c / sSc; }
        __syncthreads();
    }

    float g0 = gcm[0], g1 = gcm[1], g2 = gcm[2];
    float g3 = gcm[3], g4 = gcm[4], g5 = gcm[5];
    float g6 = gcm[6], g7 = gcm[7], g8 = gcm[8];

    // ---- phase B: 4 chunks of 32 output rows ----
    int startRow = (r0 - 18 < 0) ? 0 : r0 - 18;
    int lastHi = startRow - 1;
    for (int ckn = 0; ckn < 4; ckn++) {
        int R = r0 + ckn * 32;
        int target = R + 49; if (target > HH - 1) target = HH - 1;
        // produce tpl rows lastHi+1..target in 16-row groups
        for (int rr = lastHi + 1; rr <= target; rr += 16) {
            int nr = target - rr + 1; if (nr > 16) nr = 16;
            for (int i = tx; i < nr * 100; i += 256) {
                int lr = i / 100, c = i - lr * 100;
                int gw = c0 - 18 + c;
                float v0 = 0.f, v1 = 0.f, v2 = 0.f;
                if (gw >= 0 && gw < WW) {
                    size_t p = (size_t)(rr + lr) * WW + gw;
                    v0 = pb[p]; v1 = pb[(size_t)PIX + p]; v2 = pb[2 * (size_t)PIX + p];
                }
                xst[lr][0][c] = g0 * v0 + g1 * v1 + g2 * v2;
                xst[lr][1][c] = g3 * v0 + g4 * v1 + g5 * v2;
                xst[lr][2][c] = g6 * v0 + g7 * v1 + g8 * v2;
            }
            __syncthreads();
            int lr = tx >> 4, c4 = (tx & 15) * 4;
            if (lr < nr) {
                float a0[4] = {}, a1[4] = {}, a2[4] = {}, a3[4] = {};
#pragma unroll
                for (int k4 = 0; k4 < 10; k4++) {
                    float4 x0 = *(const float4*)&xst[lr][0][c4 + k4 * 4];
                    float4 x1 = *(const float4*)&xst[lr][1][c4 + k4 * 4];
                    float4 x2 = *(const float4*)&xst[lr][2][c4 + k4 * 4];
                    const float* s0 = (const float*)&x0;
                    const float* s1 = (const float*)&x1;
                    const float* s2 = (const float*)&x2;
#pragma unroll
                    for (int s = 0; s < 4; s++) {
                        int kk = k4 * 4 + s;
#pragma unroll
                        for (int i = 0; i < 4; i++) {
                            int k = kk - i;
                            if (k >= 0 && k < 37) {
                                float ce = leh[k], cc = lch[k];
                                a0[i] += ce * s0[s]; a1[i] += ce * s1[s];
                                a2[i] += ce * s2[s]; a3[i] += cc * s0[s];
                            }
                        }
                    }
                }
                int slot = (rr + lr) % 68;
                *(float4*)&tplb[slot][0][c4] = make_float4(a0[0], a0[1], a0[2], a0[3]);
                *(float4*)&tplb[slot][1][c4] = make_float4(a1[0], a1[1], a1[2], a1[3]);
                *(float4*)&tplb[slot][2][c4] = make_float4(a2[0], a2[1], a2[2], a2[3]);
                *(float4*)&tplb[slot][3][c4] = make_float4(a3[0], a3[1], a3[2], a3[3]);
            }
            __syncthreads();
        }
        lastHi = target;

        // consume: vert for output rows R..R+31 (8 rows/thread)
        {
            int g = tx >> 6, c = tx & 63;
            int base = R + g * 8;
            int sbase = ((base - 18) % 68 + 68) % 68;
            float E[8] = {}, Ex[8] = {}, Ey[8] = {}, El[8] = {}, Ell[8] = {};
#pragma unroll
            for (int kk = 0; kk < 44; kk++) {
                int gr = base - 18 + kk;
                if (gr >= 0 && gr < HH) {
                    int slot = sbase + kk; if (slot >= 68) slot -= 68;
                    float v0 = tplb[slot][0][c], v1 = tplb[slot][1][c];
                    float v2 = tplb[slot][2][c], v3 = tplb[slot][3][c];
#pragma unroll
                    for (int i = 0; i < 8; i++) {
                        int k = kk - i;
                        if (k >= 0 && k < 37) {
                            float ce = leh[k], cc = lch[k];
                            E[i] += ce * v0; Ex[i] += cc * v0; Ey[i] += ce * v3;
                            El[i] += ce * v1; Ell[i] += ce * v2;
                        }
                    }
                }
            }
#pragma unroll
            for (int i = 0; i < 8; i++) {
                int h = base + i;
                float Hf = atanf(El[i] / (Ell[i] + EPSF));
                float S = logf((El[i] * El[i] + Ell[i] * Ell[i]) / (E[i] * E[i] + EPSF) + EPSF);
                float rx = Ex[i] / (E[i] + EPSF), ry = Ey[i] / (E[i] + EPSF);
                float Wv = atanf(rx * rx + ry * ry);
                size_t basep = (size_t)(b * 6) * PIX + (size_t)h * WW + (c0 + c);
                out[basep] = Hf;
                out[basep + PIX] = S;
                out[basep + 5 * (size_t)PIX] = Wv;
            }
        }
        __syncthreads();   // ring rows consumed before next chunk overwrites them
    }
}

extern "C" void kernel_launch(void* const* d_in, const int* in_sizes, int n_in,
                              void* d_out, int out_size, void* d_ws, size_t ws_size,
                              hipStream_t stream) {
    const float* batch = (const float*)d_in[0];
    const float* gcm   = (const float*)d_in[1];
    const float* w1    = (const float*)d_in[2];
    const float* b1    = (const float*)d_in[3];
    const float* w2    = (const float*)d_in[4];
    const float* b2    = (const float*)d_in[5];
    const float* w3    = (const float*)d_in[6];
    const float* b3    = (const float*)d_in[7];
    float* out = (float*)d_out;

    if (ws_size < WS_NEEDED) return;
    float* wsf = (float*)d_ws;

    prep_kernel<<<dim3(1), dim3(256), 0, stream>>>(w2, wsf);
    conv12_kernel<<<dim3(8, 32, 8), dim3(256), 0, stream>>>(
        batch, w1, b1, (const unsigned short*)(wsf + OFF_WR), b2, wsf, out);
    strip_kernel<<<dim3(8, 4, 8), dim3(256), 0, stream>>>(batch, gcm, w3, b3, wsf, out);
}